// Round 1
// baseline (2107.321 us; speedup 1.0000x reference)
//
#include <hip/hip_runtime.h>
#include <hip/hip_bf16.h>
#include <stdint.h>

// Shapes: B=4, N=512, IN=1024, H=256 (MID=512), 4H=1024, OUT_K=50, N_POS=30, SE=64
// out[4][50][512][512] fp32.

typedef float  floatx4 __attribute__((ext_vector_type(4)));
typedef short  short8  __attribute__((ext_vector_type(8)));
typedef unsigned short ushort8 __attribute__((ext_vector_type(8)));
typedef int    int4v   __attribute__((ext_vector_type(4)));

__device__ __forceinline__ short f2bf(float f) {
    __hip_bfloat16 h = __float2bfloat16(f);
    return *reinterpret_cast<short*>(&h);
}
__device__ __forceinline__ float sigf(float x)  { return 1.0f / (1.0f + __expf(-x)); }
__device__ __forceinline__ float tanhf_(float x){ return 1.0f - 2.0f / (__expf(2.0f * x) + 1.0f); }
__device__ __forceinline__ int q8i(float x) {
    int q = (int)rintf(x);
    return q > 127 ? 127 : (q < -127 ? -127 : q);
}

// ---------------------------------------------------------------------------
// prep: S_size[50][32] = Ws @ emb^T ; wcat[128][512] = [Wh;0;Wt;0] ; sbias[128];
//       biasc1[2048] = bih+bhh (f|b) ; biasc2[1024] = [b_head|b_tail]
// ---------------------------------------------------------------------------
__global__ __launch_bounds__(256) void prep_k(
    const float* __restrict__ W, const float* __restrict__ emb,
    const float* __restrict__ bih_f, const float* __restrict__ bhh_f,
    const float* __restrict__ bih_b, const float* __restrict__ bhh_b,
    const float* __restrict__ b_head, const float* __restrict__ b_tail,
    float* __restrict__ ssize, float* __restrict__ wcat,
    float* __restrict__ sbias, float* __restrict__ biasc1, float* __restrict__ biasc2)
{
    const int g0 = blockIdx.x * 256 + threadIdx.x;
    const int gs = gridDim.x * 256;
    for (int i = g0; i < 1600; i += gs) {          // ssize [50][32], cols 30,31 = 0
        int k = i >> 5, pp = i & 31;
        float acc = 0.0f;
        if (pp < 30)
            for (int h = 0; h < 64; ++h)
                acc += W[(size_t)k * 1090 + 1026 + h] * emb[pp * 64 + h];
        ssize[i] = acc;
    }
    for (int i = g0; i < 128 * 512; i += gs) {     // wcat rows: 0..49=Wh, 64..113=Wt
        int r = i >> 9, h = i & 511;
        float v = 0.0f;
        if (r < 50)                    v = W[(size_t)r * 1090 + h];
        else if (r >= 64 && r < 114)   v = W[(size_t)(r - 64) * 1090 + 513 + h];
        wcat[i] = v;
    }
    for (int i = g0; i < 128; i += gs) {
        float v = 0.0f;
        if (i < 50)                    v = W[(size_t)i * 1090 + 512];
        else if (i >= 64 && i < 114)   v = W[(size_t)(i - 64) * 1090 + 1025];
        sbias[i] = v;
    }
    for (int i = g0; i < 2048; i += gs)
        biasc1[i] = (i < 1024) ? (bih_f[i] + bhh_f[i]) : (bih_b[i - 1024] + bhh_b[i - 1024]);
    for (int i = g0; i < 1024; i += gs)
        biasc2[i] = (i < 512) ? b_head[i] : b_tail[i - 512];
}

// ---------------------------------------------------------------------------
// gemm_bt: C[m][n] = sum_k A[m][k] * Brow[n][k] + bias[n], bf16 MFMA 16x16x32.
// Block tile 128x64, 4 waves each 32 (M) x 64 (N). BK=32.
// mode 0: permuted fp32 store into xg[d][t][b][vrow]   (GEMM1)
// mode 1: leaky_relu -> bf16 store, row stride 1024    (GEMM2)
// mode 2: plain fp32 store, row stride 128             (GEMM3)
// ---------------------------------------------------------------------------
__global__ __launch_bounds__(256) void gemm_bt(
    const void* __restrict__ Aptr, int a_is_bf16, int lda,
    int a_split_n, int a_split_off,
    const float* __restrict__ B0, const float* __restrict__ B1,
    int nsplit, int ldb,
    const float* __restrict__ bias, int K, int mode,
    float* __restrict__ out0, __hip_bfloat16* __restrict__ out1)
{
    __shared__ __align__(16) short As[128][48];   // stride 48 el = 96 B (conflict pad)
    __shared__ __align__(16) short Bs[64][48];
    const int tid   = threadIdx.x;
    const int nbase = blockIdx.x * 64;
    const int mbase = blockIdx.y * 128;
    const int aoff  = (nbase >= a_split_n) ? a_split_off : 0;
    const float* Bp = (nbase < nsplit) ? (B0 + (size_t)nbase * ldb)
                                       : (B1 + (size_t)(nbase - nsplit) * ldb);
    const int arow = tid >> 1, akq = (tid & 1) * 16;   // A: 128 rows x 32k, 16 el/thread
    const int brow = tid >> 2, bkq = (tid & 3) * 8;    // B: 64 rows x 32k, 8 el/thread
    const int wv = tid >> 6, ln = tid & 63, l15 = ln & 15, quad = ln >> 4;

    floatx4 acc[2][4];
#pragma unroll
    for (int i = 0; i < 2; ++i)
#pragma unroll
        for (int j = 0; j < 4; ++j) acc[i][j] = (floatx4){0.f, 0.f, 0.f, 0.f};

    const int KI = K >> 5;
    for (int kk = 0; kk < KI; ++kk) {
        short8 sa0, sa1, sb;
        if (a_is_bf16) {
            const unsigned short* A = (const unsigned short*)Aptr;
            const unsigned short* p = A + (size_t)(mbase + arow) * lda + aoff + kk * 32 + akq;
            sa0 = *(const short8*)p;
            sa1 = *(const short8*)(p + 8);
        } else {
            const float* A = (const float*)Aptr;
            const float* p = A + (size_t)(mbase + arow) * lda + aoff + kk * 32 + akq;
            floatx4 v0 = *(const floatx4*)p;
            floatx4 v1 = *(const floatx4*)(p + 4);
            floatx4 v2 = *(const floatx4*)(p + 8);
            floatx4 v3 = *(const floatx4*)(p + 12);
            sa0[0]=f2bf(v0[0]); sa0[1]=f2bf(v0[1]); sa0[2]=f2bf(v0[2]); sa0[3]=f2bf(v0[3]);
            sa0[4]=f2bf(v1[0]); sa0[5]=f2bf(v1[1]); sa0[6]=f2bf(v1[2]); sa0[7]=f2bf(v1[3]);
            sa1[0]=f2bf(v2[0]); sa1[1]=f2bf(v2[1]); sa1[2]=f2bf(v2[2]); sa1[3]=f2bf(v2[3]);
            sa1[4]=f2bf(v3[0]); sa1[5]=f2bf(v3[1]); sa1[6]=f2bf(v3[2]); sa1[7]=f2bf(v3[3]);
        }
        {
            const float* pb = Bp + (size_t)brow * ldb + kk * 32 + bkq;
            floatx4 b0 = *(const floatx4*)pb;
            floatx4 b1 = *(const floatx4*)(pb + 4);
            sb[0]=f2bf(b0[0]); sb[1]=f2bf(b0[1]); sb[2]=f2bf(b0[2]); sb[3]=f2bf(b0[3]);
            sb[4]=f2bf(b1[0]); sb[5]=f2bf(b1[1]); sb[6]=f2bf(b1[2]); sb[7]=f2bf(b1[3]);
        }
        __syncthreads();   // previous iter's MFMA reads done
        *(short8*)&As[arow][akq]     = sa0;
        *(short8*)&As[arow][akq + 8] = sa1;
        *(short8*)&Bs[brow][bkq]     = sb;
        __syncthreads();   // staging visible

        short8 a0 = *(const short8*)&As[wv * 32 + l15][quad * 8];
        short8 a1 = *(const short8*)&As[wv * 32 + 16 + l15][quad * 8];
#pragma unroll
        for (int nt = 0; nt < 4; ++nt) {
            short8 bb = *(const short8*)&Bs[nt * 16 + l15][quad * 8];
            acc[0][nt] = __builtin_amdgcn_mfma_f32_16x16x32_bf16(a0, bb, acc[0][nt], 0, 0, 0);
            acc[1][nt] = __builtin_amdgcn_mfma_f32_16x16x32_bf16(a1, bb, acc[1][nt], 0, 0, 0);
        }
    }

#pragma unroll
    for (int mt = 0; mt < 2; ++mt)
#pragma unroll
        for (int nt = 0; nt < 4; ++nt) {
            const int gc = nbase + nt * 16 + l15;
            const float bv = bias[gc];
#pragma unroll
            for (int r = 0; r < 4; ++r) {
                const int gr = mbase + wv * 32 + mt * 16 + quad * 4 + r;
                float v = acc[mt][nt][r] + bv;
                if (mode == 0) {
                    // xg[d][t][b][vrow], vrow = unit*4 + gate (gate = nn>>8, unit = nn&255)
                    const int d = gc >> 10, nn = gc & 1023;
                    const int vrow = ((nn & 255) << 2) | (nn >> 8);
                    const int t = gr & 511, b = gr >> 9;
                    out0[(((size_t)d * 512 + t) * 4 + b) * 1024 + vrow] = v;
                } else if (mode == 1) {
                    v = v < 0.0f ? 0.01f * v : v;
                    out1[(size_t)gr * 1024 + gc] = __float2bfloat16(v);
                } else {
                    out0[(size_t)gr * 128 + gc] = v;
                }
            }
        }
}

// ---------------------------------------------------------------------------
// lstm_k: 2 blocks (fwd/bwd) x 1024 threads. Whh quantized to per-row i8,
// register-resident A-frags; per-step mfma_i32_16x16x64_i8 (M=1024,N=16,K=256).
// Gate rows permuted: vrow = unit*4 + gate so each lane's 4 acc regs = i,f,g,o
// of one (unit,batch). h fed back as i8 via swizzled LDS buffer (B-frag layout).
// ---------------------------------------------------------------------------
__global__ __launch_bounds__(1024) void lstm_k(
    const float* __restrict__ Whh_f, const float* __restrict__ Whh_b,
    const float* __restrict__ xg, __hip_bfloat16* __restrict__ hcat)
{
    const int dir = blockIdx.x;
    const float* Whh = dir ? Whh_b : Whh_f;
    const float* xgd = xg + (size_t)dir * 512 * 4 * 1024;
    __shared__ __align__(16) float sm_lds[1024];
    __shared__ __align__(16) signed char hq[2][4][64][16];  // [parity][kf][lane][16 i8]
    const int tid = threadIdx.x;
    const int wv = tid >> 6, ln = tid & 63, l15 = ln & 15, quad = ln >> 4;

    // pass 1: per-vrow max|Whh| (wave-per-row, coalesced)
    for (int v = wv * 64; v < wv * 64 + 64; ++v) {
        const int orig = ((v & 3) << 8) | (v >> 2);   // gate*256 + unit
        floatx4 x = *(const floatx4*)(Whh + (size_t)orig * 256 + ln * 4);
        float m = fmaxf(fmaxf(fabsf(x[0]), fabsf(x[1])), fmaxf(fabsf(x[2]), fabsf(x[3])));
#pragma unroll
        for (int off = 32; off; off >>= 1) m = fmaxf(m, __shfl_xor(m, off, 64));
        if (ln == 0) sm_lds[v] = m;
    }
    for (int i = tid; i < 2 * 4 * 64 * 16 / 4; i += 1024) ((int*)hq)[i] = 0;
    __syncthreads();

    // pass 2: quantize Whh into register A-frags (4 M-tiles x 4 K-frags per wave)
    int4v afrag[4][4];
#pragma unroll
    for (int tt = 0; tt < 4; ++tt) {
        const int m = wv * 4 + tt;
        const int vrow = m * 16 + l15;
        const int orig = ((vrow & 3) << 8) | (vrow >> 2);
        const float sm = sm_lds[vrow];
        const float inv = sm > 1e-30f ? 127.0f / sm : 0.0f;
#pragma unroll
        for (int kf = 0; kf < 4; ++kf) {
            const float* p = Whh + (size_t)orig * 256 + kf * 64 + quad * 16;
            int4v fr;
#pragma unroll
            for (int j = 0; j < 4; ++j) {
                floatx4 w4 = *(const floatx4*)(p + j * 4);
                int b0 = q8i(w4[0] * inv), b1 = q8i(w4[1] * inv);
                int b2 = q8i(w4[2] * inv), b3 = q8i(w4[3] * inv);
                fr[j] = (b0 & 255) | ((b1 & 255) << 8) | ((b2 & 255) << 16) | (b3 << 24);
            }
            afrag[tt][kf] = fr;
        }
    }

    float c[4] = {0.f, 0.f, 0.f, 0.f};
    const bool valid = (l15 < 4);
    const int batch = l15;
    __syncthreads();

    for (int s = 0; s < 512; ++s) {
        const int t = dir ? 511 - s : s;
        const int p = s & 1;
        floatx4 xg4[4];
        if (valid) {
#pragma unroll
            for (int tt = 0; tt < 4; ++tt) {
                const int u = (wv * 4 + tt) * 4 + quad;
                xg4[tt] = *(const floatx4*)(xgd + ((size_t)t * 4 + batch) * 1024 + u * 4);
            }
        }
        int4v acc[4];
#pragma unroll
        for (int tt = 0; tt < 4; ++tt) acc[tt] = (int4v){0, 0, 0, 0};
#pragma unroll
        for (int kf = 0; kf < 4; ++kf) {
            int4v bb = *(const int4v*)&hq[p][kf][ln][0];
#pragma unroll
            for (int tt = 0; tt < 4; ++tt)
                acc[tt] = __builtin_amdgcn_mfma_i32_16x16x64_i8(afrag[tt][kf], bb, acc[tt], 0, 0, 0);
        }
        if (valid) {
            const float sc = 1.0f / 16129.0f;   // 1/127^2
#pragma unroll
            for (int tt = 0; tt < 4; ++tt) {
                const int u = (wv * 4 + tt) * 4 + quad;
                floatx4 sm4 = *(const floatx4*)&sm_lds[u * 4];
                float gi = (float)acc[tt][0] * sm4[0] * sc + xg4[tt][0];
                float gf = (float)acc[tt][1] * sm4[1] * sc + xg4[tt][1];
                float gg = (float)acc[tt][2] * sm4[2] * sc + xg4[tt][2];
                float go = (float)acc[tt][3] * sm4[3] * sc + xg4[tt][3];
                float iv = sigf(gi), fv = sigf(gf), gv = tanhf_(gg), ov = sigf(go);
                c[tt] = fv * c[tt] + iv * gv;
                float h = ov * tanhf_(c[tt]);
                hcat[((size_t)batch * 512 + t) * 512 + dir * 256 + u] = __float2bfloat16(h);
                const int hb = q8i(h * 127.0f);
                hq[p ^ 1][u >> 6][(((u >> 4) & 3) << 4) + batch][u & 15] = (signed char)hb;
            }
        }
        __syncthreads();
    }
}

// ---------------------------------------------------------------------------
// final: out[b][k][m][n] = s_head[b,m,k] + s_tail[b,n,k] + S[k][clamp(n-m)]
// ---------------------------------------------------------------------------
__global__ __launch_bounds__(256) void final_k(
    const float* __restrict__ sarr, const float* __restrict__ ssize,
    float* __restrict__ out)
{
    const int mb = blockIdx.x * 64;
    const int k  = blockIdx.y;
    const int b  = blockIdx.z;
    __shared__ float st[512];
    __shared__ float sh[64];
    __shared__ float ss[32];
    const int tid = threadIdx.x;
    for (int n = tid; n < 512; n += 256)
        st[n] = sarr[((size_t)b * 512 + n) * 128 + 64 + k];
    if (tid < 64) sh[tid] = sarr[((size_t)b * 512 + mb + tid) * 128 + k];
    if (tid < 32) ss[tid] = ssize[k * 32 + tid];
    __syncthreads();
    const int n4 = (tid & 127) * 4;
    const int m0 = tid >> 7;
    float* ob = out + (((size_t)b * 50 + k) * 512 + mb) * 512;
    for (int mi = m0; mi < 64; mi += 2) {
        const int m = mb + mi;
        const float base = sh[mi];
        floatx4 v;
#pragma unroll
        for (int e = 0; e < 4; ++e) {
            int d = n4 + e - m;
            d = d < -15 ? -15 : (d > 14 ? 14 : d);
            v[e] = base + st[n4 + e] + ss[d + 15];
        }
        *(floatx4*)(ob + (size_t)mi * 512 + n4) = v;
    }
}

// ---------------------------------------------------------------------------
extern "C" void kernel_launch(void* const* d_in, const int* in_sizes, int n_in,
                              void* d_out, int out_size, void* d_ws, size_t ws_size,
                              hipStream_t stream)
{
    const float* input_embeds = (const float*)d_in[0];
    const float* Wih_f  = (const float*)d_in[1];
    const float* Whh_f  = (const float*)d_in[2];
    const float* bih_f  = (const float*)d_in[3];
    const float* bhh_f  = (const float*)d_in[4];
    const float* Wih_b  = (const float*)d_in[5];
    const float* Whh_b  = (const float*)d_in[6];
    const float* bih_b  = (const float*)d_in[7];
    const float* bhh_b  = (const float*)d_in[8];
    const float* W_head = (const float*)d_in[9];
    const float* b_head = (const float*)d_in[10];
    const float* W_tail = (const float*)d_in[11];
    const float* b_tail = (const float*)d_in[12];
    const float* emb    = (const float*)d_in[13];
    const float* W      = (const float*)d_in[14];
    float* out = (float*)d_out;

    char* w = (char*)d_ws;
    float* xg     = (float*)w;  w += (size_t)2 * 512 * 4 * 1024 * 4;  // 16 MB
    float* biasc1 = (float*)w;  w += 2048 * 4;
    float* biasc2 = (float*)w;  w += 1024 * 4;
    float* sbias  = (float*)w;  w += 128 * 4;
    float* ssize  = (float*)w;  w += 1600 * 4;
    float* wcat   = (float*)w;  w += 65536 * 4;
    float* sarr   = (float*)w;  w += 262144 * 4;
    __hip_bfloat16* hcat = (__hip_bfloat16*)w;  w += (size_t)2048 * 512 * 2;
    __hip_bfloat16* ht   = (__hip_bfloat16*)w;  w += (size_t)2048 * 1024 * 2;

    hipLaunchKernelGGL(prep_k, dim3(64), dim3(256), 0, stream,
        W, emb, bih_f, bhh_f, bih_b, bhh_b, b_head, b_tail,
        ssize, wcat, sbias, biasc1, biasc2);

    // GEMM1: xg = X @ [Wih_f | Wih_b]^T + bias  (M=2048, N=2048, K=1024)
    hipLaunchKernelGGL(gemm_bt, dim3(32, 16), dim3(256), 0, stream,
        (const void*)input_embeds, 0, 1024, 1 << 30, 0,
        Wih_f, Wih_b, 1024, 1024, biasc1, 1024, 0, xg, (__hip_bfloat16*)nullptr);

    hipLaunchKernelGGL(lstm_k, dim3(2), dim3(1024), 0, stream, Whh_f, Whh_b, xg, hcat);

    // GEMM2: ht = leaky(hcat @ [W_head|W_tail]^T + bias)  (M=2048, N=1024, K=512)
    hipLaunchKernelGGL(gemm_bt, dim3(16, 16), dim3(256), 0, stream,
        (const void*)hcat, 1, 512, 1 << 30, 0,
        W_head, W_tail, 512, 512, biasc2, 512, 1, (float*)nullptr, ht);

    // GEMM3: sarr = ht(head|tail cols) @ wcat^T + sbias  (M=2048, N=128, K=512)
    hipLaunchKernelGGL(gemm_bt, dim3(2, 16), dim3(256), 0, stream,
        (const void*)ht, 1, 1024, 64, 512,
        wcat, wcat, 1 << 30, 512, sbias, 512, 2, sarr, (__hip_bfloat16*)nullptr);

    hipLaunchKernelGGL(final_k, dim3(8, 50, 4), dim3(256), 0, stream, sarr, ssize, out);
}

// Round 2
// 1027.774 us; speedup vs baseline: 2.0504x; 2.0504x over previous
//
#include <hip/hip_runtime.h>
#include <hip/hip_bf16.h>
#include <stdint.h>

// Shapes: B=4, N=512, IN=1024, H=256 (MID=512), 4H=1024, OUT_K=50, N_POS=30, SE=64
// out[4][50][512][512] fp32.

typedef float  floatx4 __attribute__((ext_vector_type(4)));
typedef short  short8  __attribute__((ext_vector_type(8)));
typedef int    int4v   __attribute__((ext_vector_type(4)));

__device__ __forceinline__ short f2bf(float f) {
    __hip_bfloat16 h = __float2bfloat16(f);
    return *reinterpret_cast<short*>(&h);
}
__device__ __forceinline__ float sigf(float x)  { return 1.0f / (1.0f + __expf(-x)); }
__device__ __forceinline__ float tanhf_(float x){ return 1.0f - 2.0f / (__expf(2.0f * x) + 1.0f); }
__device__ __forceinline__ int q8i(float x) {
    int q = (int)rintf(x);
    return q > 127 ? 127 : (q < -127 ? -127 : q);
}

// ---------------------------------------------------------------------------
// prep: S_size[50][32] = Ws @ emb^T ; wcat[128][512] = [Wh;0;Wt;0] ; sbias[128];
//       biasc1[2048] = bih+bhh (f|b) ; biasc2[1024] = [b_head|b_tail]
// ---------------------------------------------------------------------------
__global__ __launch_bounds__(256) void prep_k(
    const float* __restrict__ W, const float* __restrict__ emb,
    const float* __restrict__ bih_f, const float* __restrict__ bhh_f,
    const float* __restrict__ bih_b, const float* __restrict__ bhh_b,
    const float* __restrict__ b_head, const float* __restrict__ b_tail,
    float* __restrict__ ssize, float* __restrict__ wcat,
    float* __restrict__ sbias, float* __restrict__ biasc1, float* __restrict__ biasc2)
{
    const int g0 = blockIdx.x * 256 + threadIdx.x;
    const int gs = gridDim.x * 256;
    for (int i = g0; i < 1600; i += gs) {          // ssize [50][32], cols 30,31 = 0
        int k = i >> 5, pp = i & 31;
        float acc = 0.0f;
        if (pp < 30)
            for (int h = 0; h < 64; ++h)
                acc += W[(size_t)k * 1090 + 1026 + h] * emb[pp * 64 + h];
        ssize[i] = acc;
    }
    for (int i = g0; i < 128 * 512; i += gs) {     // wcat rows: 0..49=Wh, 64..113=Wt
        int r = i >> 9, h = i & 511;
        float v = 0.0f;
        if (r < 50)                    v = W[(size_t)r * 1090 + h];
        else if (r >= 64 && r < 114)   v = W[(size_t)(r - 64) * 1090 + 513 + h];
        wcat[i] = v;
    }
    for (int i = g0; i < 128; i += gs) {
        float v = 0.0f;
        if (i < 50)                    v = W[(size_t)i * 1090 + 512];
        else if (i >= 64 && i < 114)   v = W[(size_t)(i - 64) * 1090 + 1025];
        sbias[i] = v;
    }
    for (int i = g0; i < 2048; i += gs)
        biasc1[i] = (i < 1024) ? (bih_f[i] + bhh_f[i]) : (bih_b[i - 1024] + bhh_b[i - 1024]);
    for (int i = g0; i < 1024; i += gs)
        biasc2[i] = (i < 512) ? b_head[i] : b_tail[i - 512];
}

// ---------------------------------------------------------------------------
// gemm_bt: C[m][n] = sum_k A[m][k] * Brow[n][k] + bias[n], bf16 MFMA 16x16x32.
// Block tile 128x64, 4 waves each 32 (M) x 64 (N). BK=32.
// mode 0: permuted fp32 store into xg[d][t][b][vrow]   (GEMM1)
// mode 1: leaky_relu -> bf16 store, row stride 1024    (GEMM2)
// mode 2: plain fp32 store, row stride 128             (GEMM3)
// ---------------------------------------------------------------------------
__global__ __launch_bounds__(256) void gemm_bt(
    const void* __restrict__ Aptr, int a_is_bf16, int lda,
    int a_split_n, int a_split_off,
    const float* __restrict__ B0, const float* __restrict__ B1,
    int nsplit, int ldb,
    const float* __restrict__ bias, int K, int mode,
    float* __restrict__ out0, __hip_bfloat16* __restrict__ out1)
{
    __shared__ __align__(16) short As[128][48];   // stride 48 el = 96 B (conflict pad)
    __shared__ __align__(16) short Bs[64][48];
    const int tid   = threadIdx.x;
    const int nbase = blockIdx.x * 64;
    const int mbase = blockIdx.y * 128;
    const int aoff  = (nbase >= a_split_n) ? a_split_off : 0;
    const float* Bp = (nbase < nsplit) ? (B0 + (size_t)nbase * ldb)
                                       : (B1 + (size_t)(nbase - nsplit) * ldb);
    const int arow = tid >> 1, akq = (tid & 1) * 16;   // A: 128 rows x 32k, 16 el/thread
    const int brow = tid >> 2, bkq = (tid & 3) * 8;    // B: 64 rows x 32k, 8 el/thread
    const int wv = tid >> 6, ln = tid & 63, l15 = ln & 15, quad = ln >> 4;

    floatx4 acc[2][4];
#pragma unroll
    for (int i = 0; i < 2; ++i)
#pragma unroll
        for (int j = 0; j < 4; ++j) acc[i][j] = (floatx4){0.f, 0.f, 0.f, 0.f};

    const int KI = K >> 5;
    for (int kk = 0; kk < KI; ++kk) {
        short8 sa0, sa1, sb;
        if (a_is_bf16) {
            const unsigned short* A = (const unsigned short*)Aptr;
            const unsigned short* p = A + (size_t)(mbase + arow) * lda + aoff + kk * 32 + akq;
            sa0 = *(const short8*)p;
            sa1 = *(const short8*)(p + 8);
        } else {
            const float* A = (const float*)Aptr;
            const float* p = A + (size_t)(mbase + arow) * lda + aoff + kk * 32 + akq;
            floatx4 v0 = *(const floatx4*)p;
            floatx4 v1 = *(const floatx4*)(p + 4);
            floatx4 v2 = *(const floatx4*)(p + 8);
            floatx4 v3 = *(const floatx4*)(p + 12);
            sa0[0]=f2bf(v0[0]); sa0[1]=f2bf(v0[1]); sa0[2]=f2bf(v0[2]); sa0[3]=f2bf(v0[3]);
            sa0[4]=f2bf(v1[0]); sa0[5]=f2bf(v1[1]); sa0[6]=f2bf(v1[2]); sa0[7]=f2bf(v1[3]);
            sa1[0]=f2bf(v2[0]); sa1[1]=f2bf(v2[1]); sa1[2]=f2bf(v2[2]); sa1[3]=f2bf(v2[3]);
            sa1[4]=f2bf(v3[0]); sa1[5]=f2bf(v3[1]); sa1[6]=f2bf(v3[2]); sa1[7]=f2bf(v3[3]);
        }
        {
            const float* pb = Bp + (size_t)brow * ldb + kk * 32 + bkq;
            floatx4 b0 = *(const floatx4*)pb;
            floatx4 b1 = *(const floatx4*)(pb + 4);
            sb[0]=f2bf(b0[0]); sb[1]=f2bf(b0[1]); sb[2]=f2bf(b0[2]); sb[3]=f2bf(b0[3]);
            sb[4]=f2bf(b1[0]); sb[5]=f2bf(b1[1]); sb[6]=f2bf(b1[2]); sb[7]=f2bf(b1[3]);
        }
        __syncthreads();   // previous iter's MFMA reads done
        *(short8*)&As[arow][akq]     = sa0;
        *(short8*)&As[arow][akq + 8] = sa1;
        *(short8*)&Bs[brow][bkq]     = sb;
        __syncthreads();   // staging visible

        short8 a0 = *(const short8*)&As[wv * 32 + l15][quad * 8];
        short8 a1 = *(const short8*)&As[wv * 32 + 16 + l15][quad * 8];
#pragma unroll
        for (int nt = 0; nt < 4; ++nt) {
            short8 bb = *(const short8*)&Bs[nt * 16 + l15][quad * 8];
            acc[0][nt] = __builtin_amdgcn_mfma_f32_16x16x32_bf16(a0, bb, acc[0][nt], 0, 0, 0);
            acc[1][nt] = __builtin_amdgcn_mfma_f32_16x16x32_bf16(a1, bb, acc[1][nt], 0, 0, 0);
        }
    }

#pragma unroll
    for (int mt = 0; mt < 2; ++mt)
#pragma unroll
        for (int nt = 0; nt < 4; ++nt) {
            const int gc = nbase + nt * 16 + l15;
            const float bv = bias[gc];
#pragma unroll
            for (int r = 0; r < 4; ++r) {
                const int gr = mbase + wv * 32 + mt * 16 + quad * 4 + r;
                float v = acc[mt][nt][r] + bv;
                if (mode == 0) {
                    // xg[d][t][b][vrow], vrow = unit*4 + gate (gate = nn>>8, unit = nn&255)
                    const int d = gc >> 10, nn = gc & 1023;
                    const int vrow = ((nn & 255) << 2) | (nn >> 8);
                    const int t = gr & 511, b = gr >> 9;
                    out0[(((size_t)d * 512 + t) * 4 + b) * 1024 + vrow] = v;
                } else if (mode == 1) {
                    v = v < 0.0f ? 0.01f * v : v;
                    out1[(size_t)gr * 1024 + gc] = __float2bfloat16(v);
                } else {
                    out0[(size_t)gr * 128 + gc] = v;
                }
            }
        }
}

// ---------------------------------------------------------------------------
// lstm_k: 2 blocks (fwd/bwd) x 1024 threads. Whh quantized to per-row i8,
// register-resident A-frags; per-step mfma_i32_16x16x64_i8 (M=1024,N=16,K=256).
// Gate rows permuted: vrow = unit*4 + gate. After MFMA, raw i32 accs are
// lane-repacked through per-wave LDS (gexch) so ALL 64 lanes each own exactly
// one (unit,batch) gate-set -> 4x fewer wave-issue cycles on the exp/rcp-heavy
// gate math (R1 counters: active CUs were 83% VALU-issue-bound at 25% lane
// utilization). Per-unit scales preloaded to registers; xg prefetched 1 step.
// ---------------------------------------------------------------------------
__global__ __launch_bounds__(1024) void lstm_k(
    const float* __restrict__ Whh_f, const float* __restrict__ Whh_b,
    const float* __restrict__ xg, __hip_bfloat16* __restrict__ hcat)
{
    const int dir = blockIdx.x;
    const float* Whh = dir ? Whh_b : Whh_f;
    const float* xgd = xg + (size_t)dir * 512 * 4 * 1024;
    __shared__ __align__(16) float sm_lds[1024];
    __shared__ __align__(16) signed char hq[2][4][64][16];  // [parity][kf][slot][16 i8]
    __shared__ __align__(16) int gexch[16][64][4];          // per-wave repack buffer
    const int tid = threadIdx.x;
    const int wv = tid >> 6, ln = tid & 63, l15 = ln & 15, quad = ln >> 4;

    // pass 1: per-vrow max|Whh| (wave-per-row, coalesced)
    for (int v = wv * 64; v < wv * 64 + 64; ++v) {
        const int orig = ((v & 3) << 8) | (v >> 2);   // gate*256 + unit
        floatx4 x = *(const floatx4*)(Whh + (size_t)orig * 256 + ln * 4);
        float m = fmaxf(fmaxf(fabsf(x[0]), fabsf(x[1])), fmaxf(fabsf(x[2]), fabsf(x[3])));
#pragma unroll
        for (int off = 32; off; off >>= 1) m = fmaxf(m, __shfl_xor(m, off, 64));
        if (ln == 0) sm_lds[v] = m;
    }
    for (int i = tid; i < 2 * 4 * 64 * 16 / 4; i += 1024) ((int*)hq)[i] = 0;
    __syncthreads();

    // pass 2: quantize Whh into register A-frags (4 M-tiles x 4 K-frags per wave)
    int4v afrag[4][4];
#pragma unroll
    for (int tt = 0; tt < 4; ++tt) {
        const int vrow = (wv * 4 + tt) * 16 + l15;
        const int orig = ((vrow & 3) << 8) | (vrow >> 2);
        const float sm = sm_lds[vrow];
        const float inv = sm > 1e-30f ? 127.0f / sm : 0.0f;
#pragma unroll
        for (int kf = 0; kf < 4; ++kf) {
            const float* p = Whh + (size_t)orig * 256 + kf * 64 + quad * 16;
            int4v fr;
#pragma unroll
            for (int j = 0; j < 4; ++j) {
                floatx4 w4 = *(const floatx4*)(p + j * 4);
                int b0 = q8i(w4[0] * inv), b1 = q8i(w4[1] * inv);
                int b2 = q8i(w4[2] * inv), b3 = q8i(w4[3] * inv);
                fr[j] = (b0 & 255) | ((b1 & 255) << 8) | ((b2 & 255) << 16) | (b3 << 24);
            }
            afrag[tt][kf] = fr;
        }
    }

    // static per-lane gate-set assignment: unit u_mine, batch (all 64 lanes used)
    const int u_mine = wv * 16 + (ln >> 2);
    const int batch  = ln & 3;
    floatx4 scl;
    {
        const float sc = 1.0f / 16129.0f;   // 1/127^2
        floatx4 s4 = *(const floatx4*)&sm_lds[u_mine * 4];
        scl[0] = s4[0] * sc; scl[1] = s4[1] * sc; scl[2] = s4[2] * sc; scl[3] = s4[3] * sc;
    }
    // hq write slot for this lane's h value (B-frag layout, verified in R1)
    signed char* hq_w = &hq[0][u_mine >> 6][(((u_mine >> 4) & 3) << 4) + batch][u_mine & 15];
    __hip_bfloat16* hc_w = hcat + (size_t)batch * 512 * 512 + dir * 256 + u_mine;
    const float* xg_base = xgd + (size_t)batch * 1024 + u_mine * 4;

    float c = 0.0f;
    __syncthreads();

    floatx4 xg_cur = *(const floatx4*)(xg_base + (size_t)(dir ? 511 : 0) * 4096);
    for (int s = 0; s < 512; ++s) {
        const int t = dir ? 511 - s : s;
        const int p = s & 1;
        const int sn = (s + 1 < 512) ? s + 1 : s;
        const int tn = dir ? 511 - sn : sn;
        floatx4 xg_next = *(const floatx4*)(xg_base + (size_t)tn * 4096);

        int4v acc[4];
#pragma unroll
        for (int tt = 0; tt < 4; ++tt) acc[tt] = (int4v){0, 0, 0, 0};
#pragma unroll
        for (int kf = 0; kf < 4; ++kf) {
            int4v bb = *(const int4v*)&hq[p][kf][ln][0];
#pragma unroll
            for (int tt = 0; tt < 4; ++tt)
                acc[tt] = __builtin_amdgcn_mfma_i32_16x16x64_i8(afrag[tt][kf], bb, acc[tt], 0, 0, 0);
        }
        // lane repack: 16 producer lanes -> 64 consumer lanes (same wave, no barrier)
        if (l15 < 4) {
#pragma unroll
            for (int tt = 0; tt < 4; ++tt)
                *(int4v*)&gexch[wv][(tt * 4 + quad) * 4 + l15][0] = acc[tt];
        }
        int4v g = *(const int4v*)&gexch[wv][ln][0];

        float gi = fmaf((float)g[0], scl[0], xg_cur[0]);
        float gf = fmaf((float)g[1], scl[1], xg_cur[1]);
        float gg = fmaf((float)g[2], scl[2], xg_cur[2]);
        float go = fmaf((float)g[3], scl[3], xg_cur[3]);
        float iv = sigf(gi), fv = sigf(gf), gv = tanhf_(gg), ov = sigf(go);
        c = fv * c + iv * gv;
        float h = ov * tanhf_(c);
        hc_w[(size_t)t * 512] = __float2bfloat16(h);
        hq_w[(p ^ 1) ? 4096 : 0] = (signed char)q8i(h * 127.0f);

        xg_cur = xg_next;
        __syncthreads();   // hq parity buffer visible to all waves for next step
    }
}

// ---------------------------------------------------------------------------
// final: out[b][k][m][n] = s_head[b,m,k] + s_tail[b,n,k] + S[k][clamp(n-m)]
// ---------------------------------------------------------------------------
__global__ __launch_bounds__(256) void final_k(
    const float* __restrict__ sarr, const float* __restrict__ ssize,
    float* __restrict__ out)
{
    const int mb = blockIdx.x * 64;
    const int k  = blockIdx.y;
    const int b  = blockIdx.z;
    __shared__ float st[512];
    __shared__ float sh[64];
    __shared__ float ss[32];
    const int tid = threadIdx.x;
    for (int n = tid; n < 512; n += 256)
        st[n] = sarr[((size_t)b * 512 + n) * 128 + 64 + k];
    if (tid < 64) sh[tid] = sarr[((size_t)b * 512 + mb + tid) * 128 + k];
    if (tid < 32) ss[tid] = ssize[k * 32 + tid];
    __syncthreads();
    const int n4 = (tid & 127) * 4;
    const int m0 = tid >> 7;
    float* ob = out + (((size_t)b * 50 + k) * 512 + mb) * 512;
    for (int mi = m0; mi < 64; mi += 2) {
        const int m = mb + mi;
        const float base = sh[mi];
        floatx4 v;
#pragma unroll
        for (int e = 0; e < 4; ++e) {
            int d = n4 + e - m;
            d = d < -15 ? -15 : (d > 14 ? 14 : d);
            v[e] = base + st[n4 + e] + ss[d + 15];
        }
        *(floatx4*)(ob + (size_t)mi * 512 + n4) = v;
    }
}

// ---------------------------------------------------------------------------
extern "C" void kernel_launch(void* const* d_in, const int* in_sizes, int n_in,
                              void* d_out, int out_size, void* d_ws, size_t ws_size,
                              hipStream_t stream)
{
    const float* input_embeds = (const float*)d_in[0];
    const float* Wih_f  = (const float*)d_in[1];
    const float* Whh_f  = (const float*)d_in[2];
    const float* bih_f  = (const float*)d_in[3];
    const float* bhh_f  = (const float*)d_in[4];
    const float* Wih_b  = (const float*)d_in[5];
    const float* Whh_b  = (const float*)d_in[6];
    const float* bih_b  = (const float*)d_in[7];
    const float* bhh_b  = (const float*)d_in[8];
    const float* W_head = (const float*)d_in[9];
    const float* b_head = (const float*)d_in[10];
    const float* W_tail = (const float*)d_in[11];
    const float* b_tail = (const float*)d_in[12];
    const float* emb    = (const float*)d_in[13];
    const float* W      = (const float*)d_in[14];
    float* out = (float*)d_out;

    char* w = (char*)d_ws;
    float* xg     = (float*)w;  w += (size_t)2 * 512 * 4 * 1024 * 4;  // 16 MB
    float* biasc1 = (float*)w;  w += 2048 * 4;
    float* biasc2 = (float*)w;  w += 1024 * 4;
    float* sbias  = (float*)w;  w += 128 * 4;
    float* ssize  = (float*)w;  w += 1600 * 4;
    float* wcat   = (float*)w;  w += 65536 * 4;
    float* sarr   = (float*)w;  w += 262144 * 4;
    __hip_bfloat16* hcat = (__hip_bfloat16*)w;  w += (size_t)2048 * 512 * 2;
    __hip_bfloat16* ht   = (__hip_bfloat16*)w;  w += (size_t)2048 * 1024 * 2;

    hipLaunchKernelGGL(prep_k, dim3(64), dim3(256), 0, stream,
        W, emb, bih_f, bhh_f, bih_b, bhh_b, b_head, b_tail,
        ssize, wcat, sbias, biasc1, biasc2);

    // GEMM1: xg = X @ [Wih_f | Wih_b]^T + bias  (M=2048, N=2048, K=1024)
    hipLaunchKernelGGL(gemm_bt, dim3(32, 16), dim3(256), 0, stream,
        (const void*)input_embeds, 0, 1024, 1 << 30, 0,
        Wih_f, Wih_b, 1024, 1024, biasc1, 1024, 0, xg, (__hip_bfloat16*)nullptr);

    hipLaunchKernelGGL(lstm_k, dim3(2), dim3(1024), 0, stream, Whh_f, Whh_b, xg, hcat);

    // GEMM2: ht = leaky(hcat @ [W_head|W_tail]^T + bias)  (M=2048, N=1024, K=512)
    hipLaunchKernelGGL(gemm_bt, dim3(16, 16), dim3(256), 0, stream,
        (const void*)hcat, 1, 512, 1 << 30, 0,
        W_head, W_tail, 512, 512, biasc2, 512, 1, (float*)nullptr, ht);

    // GEMM3: sarr = ht(head|tail cols) @ wcat^T + sbias  (M=2048, N=128, K=512)
    hipLaunchKernelGGL(gemm_bt, dim3(2, 16), dim3(256), 0, stream,
        (const void*)ht, 1, 1024, 64, 512,
        wcat, wcat, 1 << 30, 512, sbias, 512, 2, sarr, (__hip_bfloat16*)nullptr);

    hipLaunchKernelGGL(final_k, dim3(8, 50, 4), dim3(256), 0, stream, sarr, ssize, out);
}